// Round 3
// baseline (113.161 us; speedup 1.0000x reference)
//
#include <hip/hip_runtime.h>

// Problem constants
constexpr int N = 8192;
constexpr int C = 2048;
constexpr int ND = N + 4;                        // 8196
constexpr unsigned ADJ_CHUNKS = ND / 4;          // 2049 float4 per adj row
constexpr unsigned TOTAL4 = (unsigned)ND * ADJ_CHUNKS;   // 16,793,604
constexpr size_t XNEW_ELEMS = (size_t)ND * C;    // 16785408

#define C_DIAG 0.5f
#define C_LINK 0.015609764f                      /* 1/sqrt(2*2052) */
#define C_BLK  (1.0f / 2052.0f)

// ---------------------------------------------------------------------------
// adj: single streaming pass, one float4 store per 16B, value from the
// (row, chunk) sparsity pattern. Grid-stride, capped grid (saturates all CUs,
// ~32 iterations per thread amortize launch + setup).
__global__ __launch_bounds__(256) void k_adj(float* __restrict__ adj) {
    const unsigned stride = gridDim.x * 256u;
    float4* __restrict__ out = reinterpret_cast<float4*>(adj);
    for (unsigned i4 = blockIdx.x * 256u + threadIdx.x; i4 < TOTAL4; i4 += stride) {
        const unsigned row   = i4 / ADJ_CHUNKS;          // const-div -> mul_hi
        const unsigned chunk = i4 - row * ADJ_CHUNKS;
        float4 v = make_float4(0.f, 0.f, 0.f, 0.f);
        if (row < (unsigned)N) {
            if (chunk == (row >> 2))      (&v.x)[row & 3]  = C_DIAG;  // diagonal
            else if (chunk == 2048u)      (&v.x)[row >> 11] = C_LINK; // row -> center
        } else {
            const unsigned a = row - N;
            if (chunk == 2048u)           v = make_float4(C_BLK, C_BLK, C_BLK, C_BLK);
            else if ((chunk >> 9) == a)   v = make_float4(C_LINK, C_LINK, C_LINK, C_LINK);
        }
        out[i4] = v;
    }
}

// ---------------------------------------------------------------------------
// One pass over x: per-row attention score, copy row into x_new head,
// accumulate w_row * x_row into a per-block partial. Block = 256 thr = 4
// waves; each wave owns 4 consecutive rows; block covers 16 rows.
// USE_WS: write per-block partials to ws (no atomics). else: atomic fallback.
template <bool USE_WS>
__global__ __launch_bounds__(256) void k_att(const float* __restrict__ x,
                                             const float* __restrict__ attw,
                                             const float* __restrict__ attb,
                                             float* __restrict__ xnew,
                                             float* __restrict__ part,
                                             float* __restrict__ wpart) {
    __shared__ float lnum[4][C];               // 32 KiB per-wave partials
    __shared__ float lw[4];

    const int tid  = threadIdx.x;
    const int wave = tid >> 6;
    const int lane = tid & 63;
    const int row0 = blockIdx.x * 16;
    const int seg  = blockIdx.x >> 7;          // 128 blocks per segment
    const float bias = attb[0];

    float4 wv[8];
#pragma unroll
    for (int q = 0; q < 8; ++q)
        wv[q] = reinterpret_cast<const float4*>(attw)[lane + 64 * q];

    float acc[32];
#pragma unroll
    for (int k = 0; k < 32; ++k) acc[k] = 0.0f;
    float wacc = 0.0f;

    for (int r = 0; r < 4; ++r) {
        const int row = row0 + wave * 4 + r;
        const float4* xrow = reinterpret_cast<const float4*>(x + (size_t)row * C);
        float4* orow = reinterpret_cast<float4*>(xnew + (size_t)row * C);

        float4 xv[8];
        float dot = 0.0f;
#pragma unroll
        for (int q = 0; q < 8; ++q) {
            xv[q] = xrow[lane + 64 * q];
            dot += xv[q].x * wv[q].x + xv[q].y * wv[q].y +
                   xv[q].z * wv[q].z + xv[q].w * wv[q].w;
        }
#pragma unroll
        for (int off = 32; off > 0; off >>= 1) dot += __shfl_xor(dot, off, 64);
        const float wrow = dot + bias;
        wacc += wrow;
#pragma unroll
        for (int q = 0; q < 8; ++q) {
            acc[4 * q + 0] += wrow * xv[q].x;
            acc[4 * q + 1] += wrow * xv[q].y;
            acc[4 * q + 2] += wrow * xv[q].z;
            acc[4 * q + 3] += wrow * xv[q].w;
            orow[lane + 64 * q] = xv[q];       // x_new head copy
        }
    }

#pragma unroll
    for (int q = 0; q < 8; ++q)
        reinterpret_cast<float4*>(&lnum[wave][0])[lane + 64 * q] =
            make_float4(acc[4 * q], acc[4 * q + 1], acc[4 * q + 2], acc[4 * q + 3]);
    if (lane == 0) lw[wave] = wacc;            // wacc is wave-uniform
    __syncthreads();

    const float4* l0 = reinterpret_cast<const float4*>(&lnum[0][0]);
    const float4* l1 = reinterpret_cast<const float4*>(&lnum[1][0]);
    const float4* l2 = reinterpret_cast<const float4*>(&lnum[2][0]);
    const float4* l3 = reinterpret_cast<const float4*>(&lnum[3][0]);
#pragma unroll
    for (int c4 = tid; c4 < C / 4; c4 += 256) {
        float4 a = l0[c4], b = l1[c4], cc = l2[c4], d = l3[c4];
        float4 s = make_float4(a.x + b.x + cc.x + d.x, a.y + b.y + cc.y + d.y,
                               a.z + b.z + cc.z + d.z, a.w + b.w + cc.w + d.w);
        if constexpr (USE_WS) {
            reinterpret_cast<float4*>(part + (size_t)blockIdx.x * C)[c4] = s;
        } else {
            float* dst = &xnew[(size_t)(N + seg) * C + 4 * c4];
            atomicAdd(dst + 0, s.x); atomicAdd(dst + 1, s.y);
            atomicAdd(dst + 2, s.z); atomicAdd(dst + 3, s.w);
        }
    }
    if (tid == 0) {
        const float wb = lw[0] + lw[1] + lw[2] + lw[3];
        if constexpr (USE_WS) wpart[blockIdx.x] = wb;
        else                  atomicAdd(&wpart[seg], wb);
    }
}

// ---------------------------------------------------------------------------
// centers[seg][c] = sum_k part[seg*128+k][c] / sum_k wpart[seg*128+k]
__global__ __launch_bounds__(256) void k_centers(const float* __restrict__ part,
                                                 const float* __restrict__ wpart,
                                                 float* __restrict__ xnew) {
    const int idx = blockIdx.x * 256 + threadIdx.x;   // 0..8191
    const int seg = idx >> 11;
    const int c   = idx & 2047;
    float wsum = 0.0f;
#pragma unroll 8
    for (int k = 0; k < 128; ++k) wsum += wpart[seg * 128 + k];
    float s = 0.0f;
#pragma unroll 8
    for (int k = 0; k < 128; ++k) s += part[(size_t)(seg * 128 + k) * C + c];
    xnew[(size_t)(N + seg) * C + c] = s / wsum;
}

// ---------------------------------------------------------------------------
// Fallback-path helpers (used only if ws is tiny): zero + divide.
__global__ __launch_bounds__(256) void k_zero(float* __restrict__ xnew,
                                              float* __restrict__ wseg) {
    int idx = blockIdx.x * 256 + threadIdx.x;
    if (idx < 4 * C) xnew[(size_t)N * C + idx] = 0.0f;
    if (idx < 4) wseg[idx] = 0.0f;
}
__global__ __launch_bounds__(256) void k_div(float* __restrict__ xnew,
                                             const float* __restrict__ wseg) {
    int idx = blockIdx.x * 256 + threadIdx.x;
    if (idx < 4 * C) xnew[(size_t)N * C + idx] /= wseg[idx >> 11];
}

// ---------------------------------------------------------------------------
extern "C" void kernel_launch(void* const* d_in, const int* in_sizes, int n_in,
                              void* d_out, int out_size, void* d_ws, size_t ws_size,
                              hipStream_t stream) {
    const float* x    = (const float*)d_in[0];
    const float* attw = (const float*)d_in[1];
    const float* attb = (const float*)d_in[2];
    float* xnew = (float*)d_out;                   // [8196, 2048]
    float* adj  = (float*)d_out + XNEW_ELEMS;      // [8196, 8196]

    const size_t ws_need = (1024 + (size_t)512 * C) * sizeof(float);  // ~4.2 MB
    if (ws_size >= ws_need) {
        float* wpart = (float*)d_ws;               // [512]
        float* part  = (float*)d_ws + 1024;        // [512][C]
        k_att<true><<<N / 16, 256, 0, stream>>>(x, attw, attb, xnew, part, wpart);
        k_centers<<<32, 256, 0, stream>>>(part, wpart, xnew);
    } else {                                        // atomic fallback
        float* wseg = (float*)d_ws;                // [4]
        k_zero<<<32, 256, 0, stream>>>(xnew, wseg);
        k_att<false><<<N / 16, 256, 0, stream>>>(x, attw, attb, xnew, nullptr, wseg);
        k_div<<<32, 256, 0, stream>>>(xnew, wseg);
    }

    // adj: one streaming-store pass (replaces slow runtime memset + scatter).
    k_adj<<<2048, 256, 0, stream>>>(adj);
}